// Round 3
// baseline (409.273 us; speedup 1.0000x reference)
//
#include <hip/hip_runtime.h>
#include <hip/hip_fp16.h>

#define NN 100000
#define HD 64
#define NB ((NN + 255) >> 8)   // 391 dst-buckets of 256 nodes
#define P1_CHUNK 8192

// p1: chunked bucket scatter, single pass (no pre-histogram).
// Each chunk-block builds an LDS histogram, reserves a contiguous range per bucket
// directly in the running global counter bcnt[b], then scatters packed entries into
// the bucket's FIXED-STRIDE region of ebuf: ebuf[b*ebs + rel].
// ebuf entry packed: (d & 255) << 24 | src   (src < 2^24)
__global__ __launch_bounds__(256) void p1_kernel(const int* __restrict__ src,
                                                 const int* __restrict__ dst,
                                                 int* __restrict__ bcnt,
                                                 unsigned* __restrict__ ebuf,
                                                 int E, int ebs) {
    __shared__ int hist[NB];
    __shared__ int cur[NB];
    int t = threadIdx.x;
    int e0 = blockIdx.x * P1_CHUNK;
    int count = min(P1_CHUNK, E - e0);
    for (int b = t; b < NB; b += 256) hist[b] = 0;
    __syncthreads();
    for (int i = t; i < count; i += 256) atomicAdd(&hist[dst[e0 + i] >> 8], 1);
    __syncthreads();
    for (int b = t; b < NB; b += 256) {
        int c = hist[b];
        cur[b] = c ? atomicAdd(&bcnt[b], c) : 0;
    }
    __syncthreads();
    for (int i = t; i < count; i += 256) {
        int d = dst[e0 + i], s = src[e0 + i];
        int b = d >> 8;
        int rel = atomicAdd(&cur[b], 1);
        ebuf[(size_t)b * ebs + rel] = ((unsigned)(d & 255) << 24) | (unsigned)s;
    }
}

// p2: one block per bucket. Computes its own global base S_b = sum_{i<b} bcnt[i]
// (256-thread strided reduction over NB ints), then LDS degree count + scan ->
// row_ptr/dinv, then local scatter to compact csr_src. Block 0 also writes
// row_ptr[n] = E and zeros the h pad row (gather target for padded edge slots).
__global__ __launch_bounds__(256) void p2_kernel(const unsigned* __restrict__ ebuf,
                                                 const int* __restrict__ bcnt,
                                                 int* __restrict__ row_ptr,
                                                 float* __restrict__ dinv,
                                                 int* __restrict__ csr_src,
                                                 int* __restrict__ hpad,
                                                 int n, int E, int ebs) {
    __shared__ int cnt[256];
    __shared__ int cur[256];
    __shared__ int red[256];
    int b = blockIdx.x;
    int t = threadIdx.x;
    // exclusive prefix: S = sum_{i<b} bcnt[i]
    int part = 0;
    for (int i = t; i < NB; i += 256)
        if (i < b) part += bcnt[i];
    red[t] = part;
    __syncthreads();
    for (int off = 128; off > 0; off >>= 1) {
        if (t < off) red[t] += red[t + off];
        __syncthreads();
    }
    int S = red[0];
    int cb = bcnt[b];
    const unsigned* eb = ebuf + (size_t)b * ebs;
    cnt[t] = 0;
    __syncthreads();
    for (int i = t; i < cb; i += 256) atomicAdd(&cnt[eb[i] >> 24], 1);
    __syncthreads();
    int deg = cnt[t];
    for (int off = 1; off < 256; off <<= 1) {   // inclusive scan
        int v = (t >= off) ? cnt[t - off] : 0;
        __syncthreads();
        cnt[t] += v;
        __syncthreads();
    }
    int excl = cnt[t] - deg;
    int node = (b << 8) + t;
    if (node < n) {
        row_ptr[node] = S + excl;
        dinv[node] = rsqrtf((float)deg + 1.0f);   // +1 = self loop
    }
    cur[t] = S + excl;
    __syncthreads();
    for (int i = t; i < cb; i += 256) {
        unsigned p = eb[i];
        int pos = atomicAdd(&cur[p >> 24], 1);
        csr_src[pos] = (int)(p & 0xFFFFFFu);
    }
    if (b == 0) {
        if (t == 0) row_ptr[n] = E;
        if (t < 32) hpad[t] = 0;   // zero 128B pad row of h
    }
}

// H(fp16) = (X @ W) * dinv[row] — 64x64 tile/block, 4x4 micro-tile/thread.
// Xs padded to stride 68 floats (272B, 16B-aligned) so the k-loop (step 4) reads
// A fragments as ds_read_b128: 8 b128 per 4 k's vs previous 4 b128 + 16 scalar.
// Per-acc accumulation order stays k-ascending (bit-identical numerics).
__global__ __launch_bounds__(256) void matmul64_kernel(const void* __restrict__ Xv,
                                                       int x_is_half,
                                                       const float* __restrict__ W,
                                                       const float* __restrict__ dinv,
                                                       float2* __restrict__ H, int n) {
    __shared__ float Wl[64 * 64];      // [k][c], float4-aligned
    __shared__ float Xs[64 * 68];      // [r][k], pad 68 (16B-aligned rows)
    int tid = threadIdx.x;
    int row0 = blockIdx.x * 64;
    const float4* W4 = (const float4*)W;
    float4* Wl4 = (float4*)Wl;
#pragma unroll
    for (int i = 0; i < 4; ++i) Wl4[tid + 256 * i] = W4[tid + 256 * i];
    if (x_is_half) {
        const float4* X4 = (const float4*)Xv;   // 8 fp16 per float4; row = 8 float4s
#pragma unroll
        for (int i = 0; i < 2; ++i) {
            int l = tid + 256 * i;              // 512 float4s = 64 rows x 8
            int r = l >> 3, k0 = (l & 7) * 8;
            int row = row0 + r;
            float4 xv = (row < n) ? X4[(size_t)row * 8 + (l & 7)]
                                  : make_float4(0.f, 0.f, 0.f, 0.f);
            const __half2* hp = (const __half2*)&xv;
#pragma unroll
            for (int j = 0; j < 4; ++j) {
                float2 f = __half22float2(hp[j]);
                Xs[r * 68 + k0 + 2 * j]     = f.x;
                Xs[r * 68 + k0 + 2 * j + 1] = f.y;
            }
        }
    } else {
        const float4* X4 = (const float4*)Xv;
#pragma unroll
        for (int i = 0; i < 4; ++i) {
            int l = tid + 256 * i;              // 1024 float4s = 64 rows x 16
            int r = l >> 4, k0 = (l & 15) * 4;
            int row = row0 + r;
            float4 xv = (row < n) ? X4[(size_t)row * 16 + (l & 15)]
                                  : make_float4(0.f, 0.f, 0.f, 0.f);
            Xs[r * 68 + k0 + 0] = xv.x;
            Xs[r * 68 + k0 + 1] = xv.y;
            Xs[r * 68 + k0 + 2] = xv.z;
            Xs[r * 68 + k0 + 3] = xv.w;
        }
    }
    __syncthreads();
    int tx = tid & 15, ty = tid >> 4;   // cols c0=4*tx, rows r0=4*ty
    float acc[4][4] = {};
    const float4* Wlr4 = (const float4*)Wl;
    const float4* Xs4 = (const float4*)Xs;   // row r base: r*17 float4s
#define MMR(J, A)                                                                               \
    acc[J][0] += A.x*b0.x; acc[J][1] += A.x*b0.y; acc[J][2] += A.x*b0.z; acc[J][3] += A.x*b0.w; \
    acc[J][0] += A.y*b1.x; acc[J][1] += A.y*b1.y; acc[J][2] += A.y*b1.z; acc[J][3] += A.y*b1.w; \
    acc[J][0] += A.z*b2.x; acc[J][1] += A.z*b2.y; acc[J][2] += A.z*b2.z; acc[J][3] += A.z*b2.w; \
    acc[J][0] += A.w*b3.x; acc[J][1] += A.w*b3.y; acc[J][2] += A.w*b3.z; acc[J][3] += A.w*b3.w;
#pragma unroll
    for (int k = 0; k < 64; k += 4) {
        float4 a0 = Xs4[(ty * 4 + 0) * 17 + (k >> 2)];
        float4 a1 = Xs4[(ty * 4 + 1) * 17 + (k >> 2)];
        float4 a2 = Xs4[(ty * 4 + 2) * 17 + (k >> 2)];
        float4 a3 = Xs4[(ty * 4 + 3) * 17 + (k >> 2)];
        float4 b0 = Wlr4[(k + 0) * 16 + tx];
        float4 b1 = Wlr4[(k + 1) * 16 + tx];
        float4 b2 = Wlr4[(k + 2) * 16 + tx];
        float4 b3 = Wlr4[(k + 3) * 16 + tx];
        MMR(0, a0) MMR(1, a1) MMR(2, a2) MMR(3, a3)
    }
#undef MMR
#pragma unroll
    for (int j = 0; j < 4; ++j) {
        int row = row0 + ty * 4 + j;
        if (row < n) {
            float dn = dinv[row];
            __half2 p01 = __float22half2_rn(make_float2(acc[j][0] * dn, acc[j][1] * dn));
            __half2 p23 = __float22half2_rn(make_float2(acc[j][2] * dn, acc[j][3] * dn));
            float2 st;
            st.x = *reinterpret_cast<float*>(&p01);
            st.y = *reinterpret_cast<float*>(&p23);
            H[(size_t)row * 16 + tx] = st;
        }
    }
}

#define PK_ACC(RAW) do {                                                     \
    a0 = __hadd2(a0, *reinterpret_cast<__half2*>(&(RAW).x));                 \
    a1 = __hadd2(a1, *reinterpret_cast<__half2*>(&(RAW).y));                 \
    a2 = __hadd2(a2, *reinterpret_cast<__half2*>(&(RAW).z));                 \
    a3 = __hadd2(a3, *reinterpret_cast<__half2*>(&(RAW).w));                 \
} while (0)

// one EIGHTH-wave (8 lanes) per node; lane c8 owns channels 8*c8..8*c8+7 (fp16 x8 = 16B).
// Branch-free 16-deep gather loop: out-of-range csr slots map to zero row NN in h.
// UNCHANGED (control: suspected L2 line-fill-rate floor).
__global__ void agg_kernel(const float4* __restrict__ h4, const int* __restrict__ row_ptr,
                           const int* __restrict__ csr_src, const float* __restrict__ dinv,
                           const float* __restrict__ b, const float4* __restrict__ xprev,
                           float4* __restrict__ xout, float* __restrict__ outp,
                           const float* __restrict__ Wc, const float* __restrict__ bc,
                           int n, int residual, int project) {
    int lane = threadIdx.x & 63;
    int o = lane >> 3, c8 = lane & 7;
    int wid = (blockIdx.x * blockDim.x + threadIdx.x) >> 6;
    int node = wid * 8 + o;
    bool active = node < n;
    int nc = active ? node : 0;
    int beg = row_ptr[nc], end = row_ptr[nc + 1];
    int cnt = end - beg;
    // hoisted epilogue operands (latency overlaps the gather loop)
    float dn = dinv[nc];
    const float4* b4 = (const float4*)b;
    float4 bb0 = b4[c8 * 2], bb1 = b4[c8 * 2 + 1];
    float4 rr = make_float4(0.f, 0.f, 0.f, 0.f);
    if (residual) rr = xprev[(size_t)nc * 8 + c8];   // 8 fp16
    __half2 a0, a1, a2, a3;
    {
        float4 sv = h4[(size_t)nc * 8 + c8];  // self loop (pre-scaled by dinv[src])
        a0 = *reinterpret_cast<__half2*>(&sv.x);
        a1 = *reinterpret_cast<__half2*>(&sv.y);
        a2 = *reinterpret_cast<__half2*>(&sv.z);
        a3 = *reinterpret_cast<__half2*>(&sv.w);
    }
    int base = o * 8;
    for (int k = 0; k < cnt; k += 16) {
        int p = beg + k + c8;
        int svA = (p < end) ? csr_src[p] : NN;          // NN -> zero row in h
        int svB = (p + 8 < end) ? csr_src[p + 8] : NN;
        int s0 = __shfl(svA, base + 0);
        int s1 = __shfl(svA, base + 1);
        int s2 = __shfl(svA, base + 2);
        int s3 = __shfl(svA, base + 3);
        int s4 = __shfl(svA, base + 4);
        int s5 = __shfl(svA, base + 5);
        int s6 = __shfl(svA, base + 6);
        int s7 = __shfl(svA, base + 7);
        int s8  = __shfl(svB, base + 0);
        int s9  = __shfl(svB, base + 1);
        int s10 = __shfl(svB, base + 2);
        int s11 = __shfl(svB, base + 3);
        int s12 = __shfl(svB, base + 4);
        int s13 = __shfl(svB, base + 5);
        int s14 = __shfl(svB, base + 6);
        int s15 = __shfl(svB, base + 7);
        float4 v0  = h4[(size_t)s0 * 8 + c8];
        float4 v1  = h4[(size_t)s1 * 8 + c8];
        float4 v2  = h4[(size_t)s2 * 8 + c8];
        float4 v3  = h4[(size_t)s3 * 8 + c8];
        float4 v4  = h4[(size_t)s4 * 8 + c8];
        float4 v5  = h4[(size_t)s5 * 8 + c8];
        float4 v6  = h4[(size_t)s6 * 8 + c8];
        float4 v7  = h4[(size_t)s7 * 8 + c8];
        float4 v8  = h4[(size_t)s8 * 8 + c8];
        float4 v9  = h4[(size_t)s9 * 8 + c8];
        float4 v10 = h4[(size_t)s10 * 8 + c8];
        float4 v11 = h4[(size_t)s11 * 8 + c8];
        float4 v12 = h4[(size_t)s12 * 8 + c8];
        float4 v13 = h4[(size_t)s13 * 8 + c8];
        float4 v14 = h4[(size_t)s14 * 8 + c8];
        float4 v15 = h4[(size_t)s15 * 8 + c8];
        PK_ACC(v0);  PK_ACC(v1);  PK_ACC(v2);  PK_ACC(v3);
        PK_ACC(v4);  PK_ACC(v5);  PK_ACC(v6);  PK_ACC(v7);
        PK_ACC(v8);  PK_ACC(v9);  PK_ACC(v10); PK_ACC(v11);
        PK_ACC(v12); PK_ACC(v13); PK_ACC(v14); PK_ACC(v15);
    }
    if (active) {
        float2 f0 = __half22float2(a0);
        float2 f1 = __half22float2(a1);
        float2 f2 = __half22float2(a2);
        float2 f3 = __half22float2(a3);
        float4 u, w;
        u.x = f0.x * dn + bb0.x; u.y = f0.y * dn + bb0.y;
        u.z = f1.x * dn + bb0.z; u.w = f1.y * dn + bb0.w;
        w.x = f2.x * dn + bb1.x; w.y = f2.y * dn + bb1.y;
        w.z = f3.x * dn + bb1.z; w.w = f3.y * dn + bb1.w;
        if (residual) {
            const __half2* rp = (const __half2*)&rr;
            float2 r0 = __half22float2(rp[0]);
            float2 r1 = __half22float2(rp[1]);
            float2 r2 = __half22float2(rp[2]);
            float2 r3 = __half22float2(rp[3]);
            u.x += r0.x; u.y += r0.y; u.z += r1.x; u.w += r1.y;
            w.x += r2.x; w.y += r2.y; w.z += r3.x; w.w += r3.y;
        }
        u.x = fmaxf(u.x, 0.f); u.y = fmaxf(u.y, 0.f);
        u.z = fmaxf(u.z, 0.f); u.w = fmaxf(u.w, 0.f);
        w.x = fmaxf(w.x, 0.f); w.y = fmaxf(w.y, 0.f);
        w.z = fmaxf(w.z, 0.f); w.w = fmaxf(w.w, 0.f);
        if (!project) {
            __half2 o0 = __float22half2_rn(make_float2(u.x, u.y));
            __half2 o1 = __float22half2_rn(make_float2(u.z, u.w));
            __half2 o2 = __float22half2_rn(make_float2(w.x, w.y));
            __half2 o3 = __float22half2_rn(make_float2(w.z, w.w));
            float4 st;
            st.x = *reinterpret_cast<float*>(&o0);
            st.y = *reinterpret_cast<float*>(&o1);
            st.z = *reinterpret_cast<float*>(&o2);
            st.w = *reinterpret_cast<float*>(&o3);
            xout[(size_t)node * 8 + c8] = st;
        } else {
            int cb = c8 * 8;
#pragma unroll
            for (int j = 0; j < 3; ++j) {
                float p = u.x * Wc[(cb + 0) * 3 + j] + u.y * Wc[(cb + 1) * 3 + j] +
                          u.z * Wc[(cb + 2) * 3 + j] + u.w * Wc[(cb + 3) * 3 + j] +
                          w.x * Wc[(cb + 4) * 3 + j] + w.y * Wc[(cb + 5) * 3 + j] +
                          w.z * Wc[(cb + 6) * 3 + j] + w.w * Wc[(cb + 7) * 3 + j];
                p += __shfl_down(p, 4, 8);
                p += __shfl_down(p, 2, 8);
                p += __shfl_down(p, 1, 8);
                if (c8 == 0) outp[node * 3 + j] = p + bc[j];
            }
        }
    }
}

extern "C" void kernel_launch(void* const* d_in, const int* in_sizes, int n_in,
                              void* d_out, int out_size, void* d_ws, size_t ws_size,
                              hipStream_t stream) {
    const float* x  = (const float*)d_in[0];
    const int*   ei = (const int*)d_in[1];
    const float* Ws = (const float*)d_in[2];
    const float* bs = (const float*)d_in[3];
    const float* Wc = (const float*)d_in[4];
    const float* bc = (const float*)d_in[5];
    float* out = (float*)d_out;

    int E = in_sizes[1] / 2;
    const int* src = ei;
    const int* dst = ei + E;
    int nchunks = (E + P1_CHUNK - 1) / P1_CHUNK;
    // fixed per-bucket ebuf stride: avg + 25% + 1024 slack, rounded to 256.
    // For E=1.6M: avg 4092 -> ebs 6144; overflow needs a +16-sigma bucket (never).
    int ebs = ((E / NB) + (E / NB) / 4 + 1024 + 255) & ~255;

    char* wsb = (char*)d_ws;
    size_t off = 0;
    int*      bcnt    = (int*)(wsb + off); off += 512 * 4;
    int*      row_ptr = (int*)(wsb + off); off += 100608 * 4;
    float*    dinv    = (float*)(wsb + off); off += 100352 * 4;
    int*      csr_src = (int*)(wsb + off); off += ((size_t)E + 256) * 4;
    float2*   h       = (float2*)(wsb + off); off += (size_t)(NN + 8) * HD * 2;  // fp16 h + zero pad row
    float4*   xa      = (float4*)(wsb + off); off += (size_t)NN * HD * 2;        // fp16 acts
    float4*   xb      = (float4*)(wsb + off); off += (size_t)NN * HD * 2;
    // ebuf (NB*ebs*4 = 9.6MB) is live only during p1/p2; xa (12.8MB) only during the
    // layer loop (after p2 completes, stream-ordered). Alias them to cap workspace.
    unsigned* ebuf    = (unsigned*)xa;

    // graph build: direct bucket scatter (p1) -> per-bucket CSR+deg+dinv (p2, inline prefix)
    hipMemsetAsync(bcnt, 0, 512 * sizeof(int), stream);
    p1_kernel<<<nchunks, 256, 0, stream>>>(src, dst, bcnt, ebuf, E, ebs);
    p2_kernel<<<NB, 256, 0, stream>>>(ebuf, bcnt, row_ptr, dinv, csr_src,
                                      (int*)((char*)h + (size_t)NN * HD * 2), NN, E, ebs);

    // layers (ping-pong xa/xb fp16); layer 3 fuses projection into agg epilogue
    const void* xin = (const void*)x;
    int xin_half = 0;
    float4* bufs[2] = {xa, xb};
    int agg_blocks = ((NN + 7) / 8 * 64 + 255) / 256;  // 8 nodes per wave
    for (int l = 0; l < 4; ++l) {
        float4* xout = bufs[l & 1];
        matmul64_kernel<<<(NN + 63) / 64, 256, 0, stream>>>(
            xin, xin_half, Ws + (size_t)l * HD * HD, dinv, h, NN);
        agg_kernel<<<agg_blocks, 256, 0, stream>>>(
            (const float4*)h, row_ptr, csr_src, dinv, bs + l * HD,
            (const float4*)xin, xout, out, Wc, bc, NN, l > 0, l == 3);
        xin = (const void*)xout;
        xin_half = 1;
    }
}

// Round 4
// 318.660 us; speedup vs baseline: 1.2844x; 1.2844x over previous
//
#include <hip/hip_runtime.h>
#include <hip/hip_fp16.h>

#define NN 100000
#define HD 64
#define NB ((NN + 255) >> 8)   // 391 dst-buckets of 256 nodes
#define P1_CHUNK 8192

// p1: chunked bucket scatter, single pass (no pre-histogram).
// Each chunk-block builds an LDS histogram, reserves a contiguous range per bucket
// directly in the running global counter bcnt[b], then scatters packed entries into
// the bucket's FIXED-STRIDE region of ebuf: ebuf[b*ebs + rel].
// ebuf entry packed: (d & 255) << 24 | src   (src < 2^24)
__global__ __launch_bounds__(256) void p1_kernel(const int* __restrict__ src,
                                                 const int* __restrict__ dst,
                                                 int* __restrict__ bcnt,
                                                 unsigned* __restrict__ ebuf,
                                                 int E, int ebs) {
    __shared__ int hist[NB];
    __shared__ int cur[NB];
    int t = threadIdx.x;
    int e0 = blockIdx.x * P1_CHUNK;
    int count = min(P1_CHUNK, E - e0);
    for (int b = t; b < NB; b += 256) hist[b] = 0;
    __syncthreads();
    for (int i = t; i < count; i += 256) atomicAdd(&hist[dst[e0 + i] >> 8], 1);
    __syncthreads();
    for (int b = t; b < NB; b += 256) {
        int c = hist[b];
        cur[b] = c ? atomicAdd(&bcnt[b], c) : 0;
    }
    __syncthreads();
    for (int i = t; i < count; i += 256) {
        int d = dst[e0 + i], s = src[e0 + i];
        int b = d >> 8;
        int rel = atomicAdd(&cur[b], 1);
        ebuf[(size_t)b * ebs + rel] = ((unsigned)(d & 255) << 24) | (unsigned)s;
    }
}

// p2: one block per bucket. Computes its own global base S_b = sum_{i<b} bcnt[i]
// (256-thread strided reduction over NB ints), then LDS degree count + scan ->
// row_ptr/dinv, then local scatter to compact csr_src. Block 0 also writes
// row_ptr[n] = E and zeros the h pad row (gather target for padded edge slots).
__global__ __launch_bounds__(256) void p2_kernel(const unsigned* __restrict__ ebuf,
                                                 const int* __restrict__ bcnt,
                                                 int* __restrict__ row_ptr,
                                                 float* __restrict__ dinv,
                                                 int* __restrict__ csr_src,
                                                 int* __restrict__ hpad,
                                                 int n, int E, int ebs) {
    __shared__ int cnt[256];
    __shared__ int cur[256];
    __shared__ int red[256];
    int b = blockIdx.x;
    int t = threadIdx.x;
    // exclusive prefix: S = sum_{i<b} bcnt[i]
    int part = 0;
    for (int i = t; i < NB; i += 256)
        if (i < b) part += bcnt[i];
    red[t] = part;
    __syncthreads();
    for (int off = 128; off > 0; off >>= 1) {
        if (t < off) red[t] += red[t + off];
        __syncthreads();
    }
    int S = red[0];
    int cb = bcnt[b];
    const unsigned* eb = ebuf + (size_t)b * ebs;
    cnt[t] = 0;
    __syncthreads();
    for (int i = t; i < cb; i += 256) atomicAdd(&cnt[eb[i] >> 24], 1);
    __syncthreads();
    int deg = cnt[t];
    for (int off = 1; off < 256; off <<= 1) {   // inclusive scan
        int v = (t >= off) ? cnt[t - off] : 0;
        __syncthreads();
        cnt[t] += v;
        __syncthreads();
    }
    int excl = cnt[t] - deg;
    int node = (b << 8) + t;
    if (node < n) {
        row_ptr[node] = S + excl;
        dinv[node] = rsqrtf((float)deg + 1.0f);   // +1 = self loop
    }
    cur[t] = S + excl;
    __syncthreads();
    for (int i = t; i < cb; i += 256) {
        unsigned p = eb[i];
        int pos = atomicAdd(&cur[p >> 24], 1);
        csr_src[pos] = (int)(p & 0xFFFFFFu);
    }
    if (b == 0) {
        if (t == 0) row_ptr[n] = E;
        if (t < 32) hpad[t] = 0;   // zero 128B pad row of h
    }
}

// H(fp16) = (X @ W) * dinv[row] — 64x64 tile/block, 4x4 micro-tile/thread.
// REVERTED to the proven round-1 schedule: 1 b128 B-read + 4 scalar A-reads per k,
// unroll 4. The b128-only variant (round 3) blew VGPR to 244 -> 8.5% occupancy,
// 4x regression. // VGPR ~100 here, occupancy ~25%+.
__global__ __launch_bounds__(256) void matmul64_kernel(const void* __restrict__ Xv,
                                                       int x_is_half,
                                                       const float* __restrict__ W,
                                                       const float* __restrict__ dinv,
                                                       float2* __restrict__ H, int n) {
    __shared__ float Wl[64 * 64];      // [k][c], float4-aligned
    __shared__ float Xs[64 * 65];      // [r][k], padded
    int tid = threadIdx.x;
    int row0 = blockIdx.x * 64;
    const float4* W4 = (const float4*)W;
    float4* Wl4 = (float4*)Wl;
#pragma unroll
    for (int i = 0; i < 4; ++i) Wl4[tid + 256 * i] = W4[tid + 256 * i];
    if (x_is_half) {
        const float4* X4 = (const float4*)Xv;   // 8 fp16 per float4; row = 8 float4s
#pragma unroll
        for (int i = 0; i < 2; ++i) {
            int l = tid + 256 * i;              // 512 float4s = 64 rows x 8
            int r = l >> 3, k0 = (l & 7) * 8;
            int row = row0 + r;
            float4 xv = (row < n) ? X4[(size_t)row * 8 + (l & 7)]
                                  : make_float4(0.f, 0.f, 0.f, 0.f);
            const __half2* hp = (const __half2*)&xv;
#pragma unroll
            for (int j = 0; j < 4; ++j) {
                float2 f = __half22float2(hp[j]);
                Xs[r * 65 + k0 + 2 * j]     = f.x;
                Xs[r * 65 + k0 + 2 * j + 1] = f.y;
            }
        }
    } else {
        const float4* X4 = (const float4*)Xv;
#pragma unroll
        for (int i = 0; i < 4; ++i) {
            int l = tid + 256 * i;              // 1024 float4s = 64 rows x 16
            int r = l >> 4, k0 = (l & 15) * 4;
            int row = row0 + r;
            float4 xv = (row < n) ? X4[(size_t)row * 16 + (l & 15)]
                                  : make_float4(0.f, 0.f, 0.f, 0.f);
            Xs[r * 65 + k0 + 0] = xv.x;
            Xs[r * 65 + k0 + 1] = xv.y;
            Xs[r * 65 + k0 + 2] = xv.z;
            Xs[r * 65 + k0 + 3] = xv.w;
        }
    }
    __syncthreads();
    int tx = tid & 15, ty = tid >> 4;   // cols c0=4*tx, rows r0=4*ty
    float acc[4][4] = {};
    const float4* Wlr4 = (const float4*)Wl;
#pragma unroll 4
    for (int k = 0; k < 64; ++k) {
        float4 b = Wlr4[k * 16 + tx];
        float a0 = Xs[(ty * 4 + 0) * 65 + k];
        float a1 = Xs[(ty * 4 + 1) * 65 + k];
        float a2 = Xs[(ty * 4 + 2) * 65 + k];
        float a3 = Xs[(ty * 4 + 3) * 65 + k];
        acc[0][0] += a0 * b.x; acc[0][1] += a0 * b.y; acc[0][2] += a0 * b.z; acc[0][3] += a0 * b.w;
        acc[1][0] += a1 * b.x; acc[1][1] += a1 * b.y; acc[1][2] += a1 * b.z; acc[1][3] += a1 * b.w;
        acc[2][0] += a2 * b.x; acc[2][1] += a2 * b.y; acc[2][2] += a2 * b.z; acc[2][3] += a2 * b.w;
        acc[3][0] += a3 * b.x; acc[3][1] += a3 * b.y; acc[3][2] += a3 * b.z; acc[3][3] += a3 * b.w;
    }
#pragma unroll
    for (int j = 0; j < 4; ++j) {
        int row = row0 + ty * 4 + j;
        if (row < n) {
            float dn = dinv[row];
            __half2 p01 = __float22half2_rn(make_float2(acc[j][0] * dn, acc[j][1] * dn));
            __half2 p23 = __float22half2_rn(make_float2(acc[j][2] * dn, acc[j][3] * dn));
            float2 st;
            st.x = *reinterpret_cast<float*>(&p01);
            st.y = *reinterpret_cast<float*>(&p23);
            H[(size_t)row * 16 + tx] = st;
        }
    }
}

#define PK_ACC(RAW) do {                                                     \
    a0 = __hadd2(a0, *reinterpret_cast<__half2*>(&(RAW).x));                 \
    a1 = __hadd2(a1, *reinterpret_cast<__half2*>(&(RAW).y));                 \
    a2 = __hadd2(a2, *reinterpret_cast<__half2*>(&(RAW).z));                 \
    a3 = __hadd2(a3, *reinterpret_cast<__half2*>(&(RAW).w));                 \
} while (0)

// one EIGHTH-wave (8 lanes) per node; lane c8 owns channels 8*c8..8*c8+7 (fp16 x8 = 16B).
// Branch-free 16-deep gather loop: out-of-range csr slots map to zero row NN in h.
// UNCHANGED (control: suspected L2 line-fill-rate floor).
__global__ void agg_kernel(const float4* __restrict__ h4, const int* __restrict__ row_ptr,
                           const int* __restrict__ csr_src, const float* __restrict__ dinv,
                           const float* __restrict__ b, const float4* __restrict__ xprev,
                           float4* __restrict__ xout, float* __restrict__ outp,
                           const float* __restrict__ Wc, const float* __restrict__ bc,
                           int n, int residual, int project) {
    int lane = threadIdx.x & 63;
    int o = lane >> 3, c8 = lane & 7;
    int wid = (blockIdx.x * blockDim.x + threadIdx.x) >> 6;
    int node = wid * 8 + o;
    bool active = node < n;
    int nc = active ? node : 0;
    int beg = row_ptr[nc], end = row_ptr[nc + 1];
    int cnt = end - beg;
    // hoisted epilogue operands (latency overlaps the gather loop)
    float dn = dinv[nc];
    const float4* b4 = (const float4*)b;
    float4 bb0 = b4[c8 * 2], bb1 = b4[c8 * 2 + 1];
    float4 rr = make_float4(0.f, 0.f, 0.f, 0.f);
    if (residual) rr = xprev[(size_t)nc * 8 + c8];   // 8 fp16
    __half2 a0, a1, a2, a3;
    {
        float4 sv = h4[(size_t)nc * 8 + c8];  // self loop (pre-scaled by dinv[src])
        a0 = *reinterpret_cast<__half2*>(&sv.x);
        a1 = *reinterpret_cast<__half2*>(&sv.y);
        a2 = *reinterpret_cast<__half2*>(&sv.z);
        a3 = *reinterpret_cast<__half2*>(&sv.w);
    }
    int base = o * 8;
    for (int k = 0; k < cnt; k += 16) {
        int p = beg + k + c8;
        int svA = (p < end) ? csr_src[p] : NN;          // NN -> zero row in h
        int svB = (p + 8 < end) ? csr_src[p + 8] : NN;
        int s0 = __shfl(svA, base + 0);
        int s1 = __shfl(svA, base + 1);
        int s2 = __shfl(svA, base + 2);
        int s3 = __shfl(svA, base + 3);
        int s4 = __shfl(svA, base + 4);
        int s5 = __shfl(svA, base + 5);
        int s6 = __shfl(svA, base + 6);
        int s7 = __shfl(svA, base + 7);
        int s8  = __shfl(svB, base + 0);
        int s9  = __shfl(svB, base + 1);
        int s10 = __shfl(svB, base + 2);
        int s11 = __shfl(svB, base + 3);
        int s12 = __shfl(svB, base + 4);
        int s13 = __shfl(svB, base + 5);
        int s14 = __shfl(svB, base + 6);
        int s15 = __shfl(svB, base + 7);
        float4 v0  = h4[(size_t)s0 * 8 + c8];
        float4 v1  = h4[(size_t)s1 * 8 + c8];
        float4 v2  = h4[(size_t)s2 * 8 + c8];
        float4 v3  = h4[(size_t)s3 * 8 + c8];
        float4 v4  = h4[(size_t)s4 * 8 + c8];
        float4 v5  = h4[(size_t)s5 * 8 + c8];
        float4 v6  = h4[(size_t)s6 * 8 + c8];
        float4 v7  = h4[(size_t)s7 * 8 + c8];
        float4 v8  = h4[(size_t)s8 * 8 + c8];
        float4 v9  = h4[(size_t)s9 * 8 + c8];
        float4 v10 = h4[(size_t)s10 * 8 + c8];
        float4 v11 = h4[(size_t)s11 * 8 + c8];
        float4 v12 = h4[(size_t)s12 * 8 + c8];
        float4 v13 = h4[(size_t)s13 * 8 + c8];
        float4 v14 = h4[(size_t)s14 * 8 + c8];
        float4 v15 = h4[(size_t)s15 * 8 + c8];
        PK_ACC(v0);  PK_ACC(v1);  PK_ACC(v2);  PK_ACC(v3);
        PK_ACC(v4);  PK_ACC(v5);  PK_ACC(v6);  PK_ACC(v7);
        PK_ACC(v8);  PK_ACC(v9);  PK_ACC(v10); PK_ACC(v11);
        PK_ACC(v12); PK_ACC(v13); PK_ACC(v14); PK_ACC(v15);
    }
    if (active) {
        float2 f0 = __half22float2(a0);
        float2 f1 = __half22float2(a1);
        float2 f2 = __half22float2(a2);
        float2 f3 = __half22float2(a3);
        float4 u, w;
        u.x = f0.x * dn + bb0.x; u.y = f0.y * dn + bb0.y;
        u.z = f1.x * dn + bb0.z; u.w = f1.y * dn + bb0.w;
        w.x = f2.x * dn + bb1.x; w.y = f2.y * dn + bb1.y;
        w.z = f3.x * dn + bb1.z; w.w = f3.y * dn + bb1.w;
        if (residual) {
            const __half2* rp = (const __half2*)&rr;
            float2 r0 = __half22float2(rp[0]);
            float2 r1 = __half22float2(rp[1]);
            float2 r2 = __half22float2(rp[2]);
            float2 r3 = __half22float2(rp[3]);
            u.x += r0.x; u.y += r0.y; u.z += r1.x; u.w += r1.y;
            w.x += r2.x; w.y += r2.y; w.z += r3.x; w.w += r3.y;
        }
        u.x = fmaxf(u.x, 0.f); u.y = fmaxf(u.y, 0.f);
        u.z = fmaxf(u.z, 0.f); u.w = fmaxf(u.w, 0.f);
        w.x = fmaxf(w.x, 0.f); w.y = fmaxf(w.y, 0.f);
        w.z = fmaxf(w.z, 0.f); w.w = fmaxf(w.w, 0.f);
        if (!project) {
            __half2 o0 = __float22half2_rn(make_float2(u.x, u.y));
            __half2 o1 = __float22half2_rn(make_float2(u.z, u.w));
            __half2 o2 = __float22half2_rn(make_float2(w.x, w.y));
            __half2 o3 = __float22half2_rn(make_float2(w.z, w.w));
            float4 st;
            st.x = *reinterpret_cast<float*>(&o0);
            st.y = *reinterpret_cast<float*>(&o1);
            st.z = *reinterpret_cast<float*>(&o2);
            st.w = *reinterpret_cast<float*>(&o3);
            xout[(size_t)node * 8 + c8] = st;
        } else {
            int cb = c8 * 8;
#pragma unroll
            for (int j = 0; j < 3; ++j) {
                float p = u.x * Wc[(cb + 0) * 3 + j] + u.y * Wc[(cb + 1) * 3 + j] +
                          u.z * Wc[(cb + 2) * 3 + j] + u.w * Wc[(cb + 3) * 3 + j] +
                          w.x * Wc[(cb + 4) * 3 + j] + w.y * Wc[(cb + 5) * 3 + j] +
                          w.z * Wc[(cb + 6) * 3 + j] + w.w * Wc[(cb + 7) * 3 + j];
                p += __shfl_down(p, 4, 8);
                p += __shfl_down(p, 2, 8);
                p += __shfl_down(p, 1, 8);
                if (c8 == 0) outp[node * 3 + j] = p + bc[j];
            }
        }
    }
}

extern "C" void kernel_launch(void* const* d_in, const int* in_sizes, int n_in,
                              void* d_out, int out_size, void* d_ws, size_t ws_size,
                              hipStream_t stream) {
    const float* x  = (const float*)d_in[0];
    const int*   ei = (const int*)d_in[1];
    const float* Ws = (const float*)d_in[2];
    const float* bs = (const float*)d_in[3];
    const float* Wc = (const float*)d_in[4];
    const float* bc = (const float*)d_in[5];
    float* out = (float*)d_out;

    int E = in_sizes[1] / 2;
    const int* src = ei;
    const int* dst = ei + E;
    int nchunks = (E + P1_CHUNK - 1) / P1_CHUNK;
    // fixed per-bucket ebuf stride: avg + 25% + 1024 slack, rounded to 256.
    // For E=1.6M: avg 4092 -> ebs 6144; overflow needs a +16-sigma bucket (never).
    int ebs = ((E / NB) + (E / NB) / 4 + 1024 + 255) & ~255;

    char* wsb = (char*)d_ws;
    size_t off = 0;
    int*      bcnt    = (int*)(wsb + off); off += 512 * 4;
    int*      row_ptr = (int*)(wsb + off); off += 100608 * 4;
    float*    dinv    = (float*)(wsb + off); off += 100352 * 4;
    int*      csr_src = (int*)(wsb + off); off += ((size_t)E + 256) * 4;
    float2*   h       = (float2*)(wsb + off); off += (size_t)(NN + 8) * HD * 2;  // fp16 h + zero pad row
    float4*   xa      = (float4*)(wsb + off); off += (size_t)NN * HD * 2;        // fp16 acts
    float4*   xb      = (float4*)(wsb + off); off += (size_t)NN * HD * 2;
    // ebuf (NB*ebs*4 = 9.6MB) is live only during p1/p2; xa (12.8MB) only during the
    // layer loop (after p2 completes, stream-ordered). Alias them to cap workspace.
    unsigned* ebuf    = (unsigned*)xa;

    // graph build: direct bucket scatter (p1) -> per-bucket CSR+deg+dinv (p2, inline prefix)
    hipMemsetAsync(bcnt, 0, 512 * sizeof(int), stream);
    p1_kernel<<<nchunks, 256, 0, stream>>>(src, dst, bcnt, ebuf, E, ebs);
    p2_kernel<<<NB, 256, 0, stream>>>(ebuf, bcnt, row_ptr, dinv, csr_src,
                                      (int*)((char*)h + (size_t)NN * HD * 2), NN, E, ebs);

    // layers (ping-pong xa/xb fp16); layer 3 fuses projection into agg epilogue
    const void* xin = (const void*)x;
    int xin_half = 0;
    float4* bufs[2] = {xa, xb};
    int agg_blocks = ((NN + 7) / 8 * 64 + 255) / 256;  // 8 nodes per wave
    for (int l = 0; l < 4; ++l) {
        float4* xout = bufs[l & 1];
        matmul64_kernel<<<(NN + 63) / 64, 256, 0, stream>>>(
            xin, xin_half, Ws + (size_t)l * HD * HD, dinv, h, NN);
        agg_kernel<<<agg_blocks, 256, 0, stream>>>(
            (const float4*)h, row_ptr, csr_src, dinv, bs + l * HD,
            (const float4*)xin, xout, out, Wc, bc, NN, l > 0, l == 3);
        xin = (const void*)xout;
        xin_half = 1;
    }
}

// Round 5
// 294.477 us; speedup vs baseline: 1.3898x; 1.0821x over previous
//
#include <hip/hip_runtime.h>
#include <hip/hip_fp16.h>

#define NN 100000
#define HD 64
#define NB ((NN + 255) >> 8)   // 391 dst-buckets of 256 nodes
#define P1_CHUNK 8192

typedef __attribute__((ext_vector_type(4))) float f32x4;
typedef __attribute__((ext_vector_type(8))) _Float16 f16x8;

// p1: chunked bucket scatter, single pass (no pre-histogram).
__global__ __launch_bounds__(256) void p1_kernel(const int* __restrict__ src,
                                                 const int* __restrict__ dst,
                                                 int* __restrict__ bcnt,
                                                 unsigned* __restrict__ ebuf,
                                                 int E, int ebs) {
    __shared__ int hist[NB];
    __shared__ int cur[NB];
    int t = threadIdx.x;
    int e0 = blockIdx.x * P1_CHUNK;
    int count = min(P1_CHUNK, E - e0);
    for (int b = t; b < NB; b += 256) hist[b] = 0;
    __syncthreads();
    for (int i = t; i < count; i += 256) atomicAdd(&hist[dst[e0 + i] >> 8], 1);
    __syncthreads();
    for (int b = t; b < NB; b += 256) {
        int c = hist[b];
        cur[b] = c ? atomicAdd(&bcnt[b], c) : 0;
    }
    __syncthreads();
    for (int i = t; i < count; i += 256) {
        int d = dst[e0 + i], s = src[e0 + i];
        int b = d >> 8;
        int rel = atomicAdd(&cur[b], 1);
        ebuf[(size_t)b * ebs + rel] = ((unsigned)(d & 255) << 24) | (unsigned)s;
    }
}

// p2: one block per bucket; inline exclusive prefix over bcnt, degree count+scan,
// local scatter to compact csr_src. Block 0 writes row_ptr[n]=E and zeros h pad row.
__global__ __launch_bounds__(256) void p2_kernel(const unsigned* __restrict__ ebuf,
                                                 const int* __restrict__ bcnt,
                                                 int* __restrict__ row_ptr,
                                                 float* __restrict__ dinv,
                                                 int* __restrict__ csr_src,
                                                 int* __restrict__ hpad,
                                                 int n, int E, int ebs) {
    __shared__ int cnt[256];
    __shared__ int cur[256];
    __shared__ int red[256];
    int b = blockIdx.x;
    int t = threadIdx.x;
    int part = 0;
    for (int i = t; i < NB; i += 256)
        if (i < b) part += bcnt[i];
    red[t] = part;
    __syncthreads();
    for (int off = 128; off > 0; off >>= 1) {
        if (t < off) red[t] += red[t + off];
        __syncthreads();
    }
    int S = red[0];
    int cb = bcnt[b];
    const unsigned* eb = ebuf + (size_t)b * ebs;
    cnt[t] = 0;
    __syncthreads();
    for (int i = t; i < cb; i += 256) atomicAdd(&cnt[eb[i] >> 24], 1);
    __syncthreads();
    int deg = cnt[t];
    for (int off = 1; off < 256; off <<= 1) {   // inclusive scan
        int v = (t >= off) ? cnt[t - off] : 0;
        __syncthreads();
        cnt[t] += v;
        __syncthreads();
    }
    int excl = cnt[t] - deg;
    int node = (b << 8) + t;
    if (node < n) {
        row_ptr[node] = S + excl;
        dinv[node] = rsqrtf((float)deg + 1.0f);   // +1 = self loop
    }
    cur[t] = S + excl;
    __syncthreads();
    for (int i = t; i < cb; i += 256) {
        unsigned p = eb[i];
        int pos = atomicAdd(&cur[p >> 24], 1);
        csr_src[pos] = (int)(p & 0xFFFFFFu);
    }
    if (b == 0) {
        if (t == 0) row_ptr[n] = E;
        if (t < 32) hpad[t] = 0;   // zero 128B pad row of h
    }
}

// Layer-0 matmul (fp32 X): proven round-1 schedule. 64x64 tile, 4x4 micro-tile.
__global__ __launch_bounds__(256) void matmul64_kernel(const float* __restrict__ X,
                                                       const float* __restrict__ W,
                                                       const float* __restrict__ dinv,
                                                       float2* __restrict__ H, int n) {
    __shared__ float Wl[64 * 64];      // [k][c], float4-aligned
    __shared__ float Xs[64 * 65];      // [r][k], padded
    int tid = threadIdx.x;
    int row0 = blockIdx.x * 64;
    const float4* W4 = (const float4*)W;
    float4* Wl4 = (float4*)Wl;
#pragma unroll
    for (int i = 0; i < 4; ++i) Wl4[tid + 256 * i] = W4[tid + 256 * i];
    {
        const float4* X4 = (const float4*)X;
#pragma unroll
        for (int i = 0; i < 4; ++i) {
            int l = tid + 256 * i;              // 1024 float4s = 64 rows x 16
            int r = l >> 4, k0 = (l & 15) * 4;
            int row = row0 + r;
            float4 xv = (row < n) ? X4[(size_t)row * 16 + (l & 15)]
                                  : make_float4(0.f, 0.f, 0.f, 0.f);
            Xs[r * 65 + k0 + 0] = xv.x;
            Xs[r * 65 + k0 + 1] = xv.y;
            Xs[r * 65 + k0 + 2] = xv.z;
            Xs[r * 65 + k0 + 3] = xv.w;
        }
    }
    __syncthreads();
    int tx = tid & 15, ty = tid >> 4;   // cols c0=4*tx, rows r0=4*ty
    float acc[4][4] = {};
    const float4* Wlr4 = (const float4*)Wl;
#pragma unroll 4
    for (int k = 0; k < 64; ++k) {
        float4 b = Wlr4[k * 16 + tx];
        float a0 = Xs[(ty * 4 + 0) * 65 + k];
        float a1 = Xs[(ty * 4 + 1) * 65 + k];
        float a2 = Xs[(ty * 4 + 2) * 65 + k];
        float a3 = Xs[(ty * 4 + 3) * 65 + k];
        acc[0][0] += a0 * b.x; acc[0][1] += a0 * b.y; acc[0][2] += a0 * b.z; acc[0][3] += a0 * b.w;
        acc[1][0] += a1 * b.x; acc[1][1] += a1 * b.y; acc[1][2] += a1 * b.z; acc[1][3] += a1 * b.w;
        acc[2][0] += a2 * b.x; acc[2][1] += a2 * b.y; acc[2][2] += a2 * b.z; acc[2][3] += a2 * b.w;
        acc[3][0] += a3 * b.x; acc[3][1] += a3 * b.y; acc[3][2] += a3 * b.z; acc[3][3] += a3 * b.w;
    }
#pragma unroll
    for (int j = 0; j < 4; ++j) {
        int row = row0 + ty * 4 + j;
        if (row < n) {
            float dn = dinv[row];
            __half2 p01 = __float22half2_rn(make_float2(acc[j][0] * dn, acc[j][1] * dn));
            __half2 p23 = __float22half2_rn(make_float2(acc[j][2] * dn, acc[j][3] * dn));
            float2 st;
            st.x = *reinterpret_cast<float*>(&p01);
            st.y = *reinterpret_cast<float*>(&p23);
            H[(size_t)row * 16 + tx] = st;
        }
    }
}

// Layers 1-3 matmul (fp16 X): MFMA 16x16x32_f16, fp32 accumulate.
// 256 threads = 4 waves; block tile 64 rows x 64 cols; wave w owns rows w*16..+15.
// A fragments load STRAIGHT from global: lane l reads X[row0+(l&15)][ (l>>4)*8 ..+7 ]
// (16B contiguous) for k-half 0, +32 halves for k-half 1 — row-major fp16 X matches
// the fragment layout exactly. B = W^T staged in LDS as fp16, rows padded to 72
// halves (stride 36 dwords -> 2-way bank aliasing = free).
// C layout (m89-verified): col = lane&15, row = (lane>>4)*4 + reg.
__global__ __launch_bounds__(256) void matmul_mfma_kernel(const __half* __restrict__ X,
                                                          const float* __restrict__ W,
                                                          const float* __restrict__ dinv,
                                                          __half* __restrict__ H, int n) {
    __shared__ _Float16 Wt[64][72];   // Wt[n][k] = W[k][n], fp16
    int tid = threadIdx.x;
    for (int i = tid; i < 4096; i += 256) {
        int k = i >> 6, nc = i & 63;
        Wt[nc][k] = (_Float16)W[i];
    }
    __syncthreads();
    int wave = tid >> 6, lane = tid & 63;
    int lrow = lane & 15, lk = lane >> 4;          // row-in-tile, k-group
    int row0 = blockIdx.x * 64 + wave * 16;
    int rc = min(row0 + lrow, n - 1);              // clamp: OOB A-rows only feed OOB C-rows
    const f16x8* Xr = (const f16x8*)(X + (size_t)rc * 64);
    f16x8 a0 = Xr[lk];                             // k = lk*8 .. +7
    f16x8 a1 = Xr[lk + 4];                         // k = 32 + lk*8 .. +7
    f32x4 acc[4] = {};
#pragma unroll
    for (int t = 0; t < 4; ++t) {
        f16x8 bl = *(const f16x8*)&Wt[16 * t + lrow][lk * 8];
        f16x8 bh = *(const f16x8*)&Wt[16 * t + lrow][32 + lk * 8];
        acc[t] = __builtin_amdgcn_mfma_f32_16x16x32_f16(a0, bl, acc[t], 0, 0, 0);
        acc[t] = __builtin_amdgcn_mfma_f32_16x16x32_f16(a1, bh, acc[t], 0, 0, 0);
    }
#pragma unroll
    for (int j = 0; j < 4; ++j) {
        int orow = row0 + lk * 4 + j;
        if (orow < n) {
            float dn = dinv[orow];
#pragma unroll
            for (int t = 0; t < 4; ++t)
                H[(size_t)orow * 64 + 16 * t + lrow] = __float2half(acc[t][j] * dn);
        }
    }
}

#define PK_ACC(RAW) do {                                                     \
    a0 = __hadd2(a0, *reinterpret_cast<__half2*>(&(RAW).x));                 \
    a1 = __hadd2(a1, *reinterpret_cast<__half2*>(&(RAW).y));                 \
    a2 = __hadd2(a2, *reinterpret_cast<__half2*>(&(RAW).z));                 \
    a3 = __hadd2(a3, *reinterpret_cast<__half2*>(&(RAW).w));                 \
} while (0)

// one EIGHTH-wave (8 lanes) per node; lane c8 owns channels 8*c8..8*c8+7 (fp16 x8 = 16B).
// Branch-free 16-deep gather loop: out-of-range csr slots map to zero row NN in h.
// UNCHANGED (control: at the ~0.9 line/cycle/XCD L2 fill-rate floor).
__global__ void agg_kernel(const float4* __restrict__ h4, const int* __restrict__ row_ptr,
                           const int* __restrict__ csr_src, const float* __restrict__ dinv,
                           const float* __restrict__ b, const float4* __restrict__ xprev,
                           float4* __restrict__ xout, float* __restrict__ outp,
                           const float* __restrict__ Wc, const float* __restrict__ bc,
                           int n, int residual, int project) {
    int lane = threadIdx.x & 63;
    int o = lane >> 3, c8 = lane & 7;
    int wid = (blockIdx.x * blockDim.x + threadIdx.x) >> 6;
    int node = wid * 8 + o;
    bool active = node < n;
    int nc = active ? node : 0;
    int beg = row_ptr[nc], end = row_ptr[nc + 1];
    int cnt = end - beg;
    float dn = dinv[nc];
    const float4* b4 = (const float4*)b;
    float4 bb0 = b4[c8 * 2], bb1 = b4[c8 * 2 + 1];
    float4 rr = make_float4(0.f, 0.f, 0.f, 0.f);
    if (residual) rr = xprev[(size_t)nc * 8 + c8];   // 8 fp16
    __half2 a0, a1, a2, a3;
    {
        float4 sv = h4[(size_t)nc * 8 + c8];  // self loop (pre-scaled by dinv[src])
        a0 = *reinterpret_cast<__half2*>(&sv.x);
        a1 = *reinterpret_cast<__half2*>(&sv.y);
        a2 = *reinterpret_cast<__half2*>(&sv.z);
        a3 = *reinterpret_cast<__half2*>(&sv.w);
    }
    int base = o * 8;
    for (int k = 0; k < cnt; k += 16) {
        int p = beg + k + c8;
        int svA = (p < end) ? csr_src[p] : NN;          // NN -> zero row in h
        int svB = (p + 8 < end) ? csr_src[p + 8] : NN;
        int s0 = __shfl(svA, base + 0);
        int s1 = __shfl(svA, base + 1);
        int s2 = __shfl(svA, base + 2);
        int s3 = __shfl(svA, base + 3);
        int s4 = __shfl(svA, base + 4);
        int s5 = __shfl(svA, base + 5);
        int s6 = __shfl(svA, base + 6);
        int s7 = __shfl(svA, base + 7);
        int s8  = __shfl(svB, base + 0);
        int s9  = __shfl(svB, base + 1);
        int s10 = __shfl(svB, base + 2);
        int s11 = __shfl(svB, base + 3);
        int s12 = __shfl(svB, base + 4);
        int s13 = __shfl(svB, base + 5);
        int s14 = __shfl(svB, base + 6);
        int s15 = __shfl(svB, base + 7);
        float4 v0  = h4[(size_t)s0 * 8 + c8];
        float4 v1  = h4[(size_t)s1 * 8 + c8];
        float4 v2  = h4[(size_t)s2 * 8 + c8];
        float4 v3  = h4[(size_t)s3 * 8 + c8];
        float4 v4  = h4[(size_t)s4 * 8 + c8];
        float4 v5  = h4[(size_t)s5 * 8 + c8];
        float4 v6  = h4[(size_t)s6 * 8 + c8];
        float4 v7  = h4[(size_t)s7 * 8 + c8];
        float4 v8  = h4[(size_t)s8 * 8 + c8];
        float4 v9  = h4[(size_t)s9 * 8 + c8];
        float4 v10 = h4[(size_t)s10 * 8 + c8];
        float4 v11 = h4[(size_t)s11 * 8 + c8];
        float4 v12 = h4[(size_t)s12 * 8 + c8];
        float4 v13 = h4[(size_t)s13 * 8 + c8];
        float4 v14 = h4[(size_t)s14 * 8 + c8];
        float4 v15 = h4[(size_t)s15 * 8 + c8];
        PK_ACC(v0);  PK_ACC(v1);  PK_ACC(v2);  PK_ACC(v3);
        PK_ACC(v4);  PK_ACC(v5);  PK_ACC(v6);  PK_ACC(v7);
        PK_ACC(v8);  PK_ACC(v9);  PK_ACC(v10); PK_ACC(v11);
        PK_ACC(v12); PK_ACC(v13); PK_ACC(v14); PK_ACC(v15);
    }
    if (active) {
        float2 f0 = __half22float2(a0);
        float2 f1 = __half22float2(a1);
        float2 f2 = __half22float2(a2);
        float2 f3 = __half22float2(a3);
        float4 u, w;
        u.x = f0.x * dn + bb0.x; u.y = f0.y * dn + bb0.y;
        u.z = f1.x * dn + bb0.z; u.w = f1.y * dn + bb0.w;
        w.x = f2.x * dn + bb1.x; w.y = f2.y * dn + bb1.y;
        w.z = f3.x * dn + bb1.z; w.w = f3.y * dn + bb1.w;
        if (residual) {
            const __half2* rp = (const __half2*)&rr;
            float2 r0 = __half22float2(rp[0]);
            float2 r1 = __half22float2(rp[1]);
            float2 r2 = __half22float2(rp[2]);
            float2 r3 = __half22float2(rp[3]);
            u.x += r0.x; u.y += r0.y; u.z += r1.x; u.w += r1.y;
            w.x += r2.x; w.y += r2.y; w.z += r3.x; w.w += r3.y;
        }
        u.x = fmaxf(u.x, 0.f); u.y = fmaxf(u.y, 0.f);
        u.z = fmaxf(u.z, 0.f); u.w = fmaxf(u.w, 0.f);
        w.x = fmaxf(w.x, 0.f); w.y = fmaxf(w.y, 0.f);
        w.z = fmaxf(w.z, 0.f); w.w = fmaxf(w.w, 0.f);
        if (!project) {
            __half2 o0 = __float22half2_rn(make_float2(u.x, u.y));
            __half2 o1 = __float22half2_rn(make_float2(u.z, u.w));
            __half2 o2 = __float22half2_rn(make_float2(w.x, w.y));
            __half2 o3 = __float22half2_rn(make_float2(w.z, w.w));
            float4 st;
            st.x = *reinterpret_cast<float*>(&o0);
            st.y = *reinterpret_cast<float*>(&o1);
            st.z = *reinterpret_cast<float*>(&o2);
            st.w = *reinterpret_cast<float*>(&o3);
            xout[(size_t)node * 8 + c8] = st;
        } else {
            int cb = c8 * 8;
#pragma unroll
            for (int j = 0; j < 3; ++j) {
                float p = u.x * Wc[(cb + 0) * 3 + j] + u.y * Wc[(cb + 1) * 3 + j] +
                          u.z * Wc[(cb + 2) * 3 + j] + u.w * Wc[(cb + 3) * 3 + j] +
                          w.x * Wc[(cb + 4) * 3 + j] + w.y * Wc[(cb + 5) * 3 + j] +
                          w.z * Wc[(cb + 6) * 3 + j] + w.w * Wc[(cb + 7) * 3 + j];
                p += __shfl_down(p, 4, 8);
                p += __shfl_down(p, 2, 8);
                p += __shfl_down(p, 1, 8);
                if (c8 == 0) outp[node * 3 + j] = p + bc[j];
            }
        }
    }
}

extern "C" void kernel_launch(void* const* d_in, const int* in_sizes, int n_in,
                              void* d_out, int out_size, void* d_ws, size_t ws_size,
                              hipStream_t stream) {
    const float* x  = (const float*)d_in[0];
    const int*   ei = (const int*)d_in[1];
    const float* Ws = (const float*)d_in[2];
    const float* bs = (const float*)d_in[3];
    const float* Wc = (const float*)d_in[4];
    const float* bc = (const float*)d_in[5];
    float* out = (float*)d_out;

    int E = in_sizes[1] / 2;
    const int* src = ei;
    const int* dst = ei + E;
    int nchunks = (E + P1_CHUNK - 1) / P1_CHUNK;
    // fixed per-bucket ebuf stride: avg + 25% + 1024 slack, rounded to 256.
    int ebs = ((E / NB) + (E / NB) / 4 + 1024 + 255) & ~255;

    char* wsb = (char*)d_ws;
    size_t off = 0;
    int*      bcnt    = (int*)(wsb + off); off += 512 * 4;
    int*      row_ptr = (int*)(wsb + off); off += 100608 * 4;
    float*    dinv    = (float*)(wsb + off); off += 100352 * 4;
    int*      csr_src = (int*)(wsb + off); off += ((size_t)E + 256) * 4;
    float2*   h       = (float2*)(wsb + off); off += (size_t)(NN + 8) * HD * 2;  // fp16 h + zero pad row
    float4*   xa      = (float4*)(wsb + off); off += (size_t)NN * HD * 2;        // fp16 acts
    float4*   xb      = (float4*)(wsb + off); off += (size_t)NN * HD * 2;
    // ebuf (9.6MB) live only during p1/p2; xa (12.8MB) only during layers. Alias.
    unsigned* ebuf    = (unsigned*)xa;

    // graph build
    hipMemsetAsync(bcnt, 0, 512 * sizeof(int), stream);
    p1_kernel<<<nchunks, 256, 0, stream>>>(src, dst, bcnt, ebuf, E, ebs);
    p2_kernel<<<NB, 256, 0, stream>>>(ebuf, bcnt, row_ptr, dinv, csr_src,
                                      (int*)((char*)h + (size_t)NN * HD * 2), NN, E, ebs);

    // layers (ping-pong xa/xb fp16); layer 3 fuses projection into agg epilogue
    const void* xin = (const void*)x;
    float4* bufs[2] = {xa, xb};
    int agg_blocks = ((NN + 7) / 8 * 64 + 255) / 256;  // 8 nodes per wave
    for (int l = 0; l < 4; ++l) {
        float4* xout = bufs[l & 1];
        if (l == 0) {
            matmul64_kernel<<<(NN + 63) / 64, 256, 0, stream>>>(
                x, Ws, dinv, h, NN);
        } else {
            matmul_mfma_kernel<<<(NN + 63) / 64, 256, 0, stream>>>(
                (const __half*)xin, Ws + (size_t)l * HD * HD, dinv, (__half*)h, NN);
        }
        agg_kernel<<<agg_blocks, 256, 0, stream>>>(
            (const float4*)h, row_ptr, csr_src, dinv, bs + l * HD,
            (const float4*)xin, xout, out, Wc, bc, NN, l > 0, l == 3);
        xin = (const void*)xout;
    }
}